// Round 6
// baseline (221.521 us; speedup 1.0000x reference)
//
#include <hip/hip_runtime.h>

#define N_NODES 8192
#define N_EDGES 262144
#define D 256
#define ADJ_WORDS 256     // 8192 bits per row / 32
#define MAX_DEG 128       // Poisson(33): P(deg>128) ~ 1e-40
#define AGG_BLOCKS 2048   // 4 waves/block, ONE row per wave -> 8192 waves
#define NPART 16          // BN partial-sum rows (atomicAdd fan-in: 2048/16 = 128 per addr)

typedef __attribute__((ext_vector_type(8))) short bf16x8;
typedef __attribute__((ext_vector_type(4))) float f32x4;
typedef __attribute__((ext_vector_type(4))) unsigned u32x4;

__device__ __forceinline__ short f2bf(float f) {
    unsigned u = __builtin_bit_cast(unsigned, f);
    u += 0x7fffu + ((u >> 16) & 1);   // round to nearest even
    return (short)(u >> 16);
}
__device__ __forceinline__ float bf2f(unsigned short u) {
    return __builtin_bit_cast(float, ((unsigned)u) << 16);
}
// one instruction, 2 values, exact RNE (identical to f2bf for finite inputs)
__device__ __forceinline__ unsigned cvt_pk(float lo, float hi) {
    unsigned r;
    asm("v_cvt_pk_bf16_f32 %0, %1, %2" : "=v"(r) : "v"(lo), "v"(hi));
    return r;
}

// ---- adjacency build (set-semantics bitmask + exact degree) + W->bf16 tail blocks ----
__global__ __launch_bounds__(256) void build_adj(const int* __restrict__ ei,
                                                 unsigned* __restrict__ adj,
                                                 int* __restrict__ deg,
                                                 const float* __restrict__ W1,
                                                 const float* __restrict__ W2,
                                                 const float* __restrict__ W3,
                                                 unsigned short* __restrict__ Wb1,
                                                 unsigned short* __restrict__ Wb2,
                                                 unsigned short* __restrict__ Wb3) {
    int i = blockIdx.x * 256 + threadIdx.x;
    if (i >= N_EDGES + N_NODES) {      // weight-conversion tail
        int j = i - (N_EDGES + N_NODES);          // 0 .. 196607
        int which = j >> 16, k = j & 65535;
        const float* src = which == 0 ? W1 : which == 1 ? W2 : W3;
        unsigned short* dst = which == 0 ? Wb1 : which == 1 ? Wb2 : Wb3;
        dst[k] = (unsigned short)f2bf(src[k]);
        return;
    }
    int r, c;
    if (i < N_EDGES) {
        r = ei[i];
        c = ei[N_EDGES + i];
    } else {
        r = i - N_EDGES;               // self loop
        c = r;
    }
    unsigned bit = 1u << (c & 31);
    unsigned old = atomicOr(&adj[r * ADJ_WORDS + (c >> 5)], bit);
    if (!(old & bit)) atomicAdd(&deg[r], 1);   // count only newly-set bits (set semantics)
}

// ----- bitmask -> neighbor index list, ONE WAVE per row (LDS-free, sync-free).
// Lane l owns words 4l..4l+3 (one uint4 = 16B load covers the whole 1KB row per wave).
// popc -> wave shuffle prefix scan -> per-lane bit extraction. -----
__device__ __forceinline__ void nbrs_row_wave(const unsigned* __restrict__ adj,
                                              int* __restrict__ nbr_idx, int r) {
    const int lane = threadIdx.x & 63;
    uint4 w = *(const uint4*)(adj + (size_t)r * ADJ_WORDS + lane * 4);
    int cnt = __popc(w.x) + __popc(w.y) + __popc(w.z) + __popc(w.w);
    int x = cnt;
    #pragma unroll
    for (int off = 1; off < 64; off <<= 1) {
        int v = __shfl_up(x, off, 64);
        if (lane >= off) x += v;
    }
    int base = x - cnt;                // exclusive prefix across the wave
    int* oi = nbr_idx + (size_t)r * MAX_DEG;
    unsigned ws[4] = {w.x, w.y, w.z, w.w};
    #pragma unroll
    for (int k = 0; k < 4; k++) {
        unsigned m = ws[k];
        const int cbase = (lane * 4 + k) * 32;
        while (m) {
            int b = __ffs(m) - 1;
            m &= m - 1;
            if (base < MAX_DEG) oi[base] = cbase + b;
            base++;
        }
    }
}

// -------- Hb(bf16) = dinv[m] * (bnapply(Xsrc fp32) @ W^T + b)  (MFMA 16x16x32 bf16) ----
// 64m x 128n tile (256 blocks = 1/CU): X conversion redundancy 4x->2x vs 64n tiles,
// G re-read 32->16 MB. All fp32->bf16 via v_cvt_pk_bf16_f32 (1 inst / 2 vals).
// BN finalize folded in: APPLY blocks reduce NPART(16) atomic partial rows.
// dinv[m] = rsqrt(deg[m]) folded into the epilogue store (weight factoring).
template <bool APPLY, bool RELU>
__device__ __forceinline__ void gemm_body(const float* __restrict__ Xsrc,
                                          const float* __restrict__ psA,
                                          const float* __restrict__ psQ,
                                          const float* __restrict__ g,
                                          const float* __restrict__ be,
                                          const unsigned short* __restrict__ Wb,
                                          const float* __restrict__ bias,
                                          const int* __restrict__ deg,
                                          unsigned short* __restrict__ Hb,
                                          int bn, int bm) {
    __shared__ float ssc[256], ssh[256];
    const int tid = threadIdx.x;
    if (APPLY) {
        float s = 0.f, q = 0.f;
        #pragma unroll
        for (int i = 0; i < NPART; i++) {
            s += psA[i * 256 + tid];
            q += psQ[i * 256 + tid];
        }
        float mu = s * (1.0f / N_NODES);
        float var = q * (1.0f / N_NODES) - mu * mu;
        float rstd = rsqrtf(var + 1e-5f);
        float sc = g[tid] * rstd;
        ssc[tid] = sc;
        ssh[tid] = be[tid] - mu * sc;
        __syncthreads();
    }

    const int wave = tid >> 6, lane = tid & 63;
    const int l16 = lane & 15, q = lane >> 4;
    const int mrow = bm + wave * 16 + l16;      // each wave owns a 16-row m-frag

    f32x4 acc[8];
    #pragma unroll
    for (int j = 0; j < 8; j++) acc[j] = (f32x4){0.f, 0.f, 0.f, 0.f};

    for (int k0 = 0; k0 < D; k0 += 32) {
        const int kq = k0 + q * 8;
        bf16x8 xb;
        {
            const float* xr = Xsrc + (size_t)mrow * D + kq;
            float4 a = *(const float4*)xr;
            float4 b = *(const float4*)(xr + 4);
            float v[8] = {a.x, a.y, a.z, a.w, b.x, b.y, b.z, b.w};
            if (APPLY) {
                float4 sc0 = *(const float4*)(ssc + kq);
                float4 sc1 = *(const float4*)(ssc + kq + 4);
                float4 sh0 = *(const float4*)(ssh + kq);
                float4 sh1 = *(const float4*)(ssh + kq + 4);
                float sc[8] = {sc0.x, sc0.y, sc0.z, sc0.w, sc1.x, sc1.y, sc1.z, sc1.w};
                float sh[8] = {sh0.x, sh0.y, sh0.z, sh0.w, sh1.x, sh1.y, sh1.z, sh1.w};
                #pragma unroll
                for (int j = 0; j < 8; j++) {
                    v[j] = fmaf(v[j], sc[j], sh[j]);
                    if (RELU) v[j] = fmaxf(v[j], 0.0f);
                }
            }
            u32x4 p;
            p.x = cvt_pk(v[0], v[1]);
            p.y = cvt_pk(v[2], v[3]);
            p.z = cvt_pk(v[4], v[5]);
            p.w = cvt_pk(v[6], v[7]);
            xb = __builtin_bit_cast(bf16x8, p);
        }
        #pragma unroll
        for (int nf = 0; nf < 8; nf++) {
            bf16x8 wa = *(const bf16x8*)(Wb + (size_t)(bn + nf * 16 + l16) * D + kq);
            acc[nf] = __builtin_amdgcn_mfma_f32_16x16x32_bf16(wa, xb, acc[nf], 0, 0, 0);
        }
    }

    const float di = rsqrtf((float)deg[mrow]);  // fold dinv[m] into stored row
    #pragma unroll
    for (int nf = 0; nf < 8; nf++) {
        const int nb = bn + nf * 16 + q * 4;
        float4 b4 = *(const float4*)(bias + nb);
        uint2 o;
        o.x = cvt_pk((acc[nf][0] + b4.x) * di, (acc[nf][1] + b4.y) * di);
        o.y = cvt_pk((acc[nf][2] + b4.z) * di, (acc[nf][3] + b4.w) * di);
        *(uint2*)(Hb + (size_t)mrow * D + nb) = o;
    }
}

// ---- fused dispatch: layer-1 gemm (256 blocks, launched first) + build_nbrs
// (2048 blocks x 4 wave-rows, LDS/sync-free) — independent work co-scheduled ----
__global__ __launch_bounds__(256) void gemm1_and_nbrs(const float* __restrict__ x,
                                                      const unsigned short* __restrict__ Wb1,
                                                      const float* __restrict__ b1,
                                                      const int* __restrict__ deg,
                                                      unsigned short* __restrict__ Hb,
                                                      const unsigned* __restrict__ adj,
                                                      int* __restrict__ nbr_idx) {
    const int bg = blockIdx.x;
    if (bg < 256) {
        gemm_body<false, false>(x, nullptr, nullptr, nullptr, nullptr, Wb1, b1, deg, Hb,
                                (bg & 1) * 128, (bg >> 1) * 64);
    } else {
        const int r = (bg - 256) * 4 + (threadIdx.x >> 6);   // 4 rows per block, 1/wave
        nbrs_row_wave(adj, nbr_idx, r);
    }
}

__global__ __launch_bounds__(256) void gemm_mfma_bn(const float* __restrict__ Xsrc,
                                                    const float* __restrict__ psA,
                                                    const float* __restrict__ psQ,
                                                    const float* __restrict__ g,
                                                    const float* __restrict__ be,
                                                    const unsigned short* __restrict__ Wb,
                                                    const float* __restrict__ bias,
                                                    const int* __restrict__ deg,
                                                    unsigned short* __restrict__ Hb) {
    gemm_body<true, true>(Xsrc, psA, psQ, g, be, Wb, bias, deg, Hb,
                          blockIdx.x * 128, blockIdx.y * 64);
}

// ------- G[r,:] = dinv[r] * sum_j Hb[idx_j,:]  (Hb rows pre-scaled by dinv[c]).
// ONE row per wave, 64 lanes x ushort4 (8B) = one full row per load instruction.
// 16-deep main loop -> 16 independent gathers in flight per wave. idx loads int4.
// BN partials: LDS block-reduce then atomicAdd into NPART(16) partial rows. -------
__global__ __launch_bounds__(256) void aggregate_bf16(const int* __restrict__ nbr_idx,
                                                      const int* __restrict__ deg,
                                                      const unsigned short* __restrict__ Hb,
                                                      float* __restrict__ G,
                                                      float* __restrict__ psA,
                                                      float* __restrict__ psQ) {
    const int wave = threadIdx.x >> 6;
    const int lane = threadIdx.x & 63;
    const int ch = lane * 4;             // 4 channels per lane, 64 lanes = full row
    const int r = blockIdx.x * 4 + wave;

    const int dgr = deg[r];
    int dg = dgr; if (dg > MAX_DEG) dg = MAX_DEG;
    const int* idx = nbr_idx + (size_t)r * MAX_DEG;
    const unsigned short* hb = Hb + ch;

    float a0 = 0.f, a1 = 0.f, a2 = 0.f, a3 = 0.f;
    int base = 0;
    for (; base + 16 <= dg; base += 16) {         // 16 x 8B gathers in flight
        int4 q0 = *(const int4*)(idx + base);
        int4 q1 = *(const int4*)(idx + base + 4);
        int4 q2 = *(const int4*)(idx + base + 8);
        int4 q3 = *(const int4*)(idx + base + 12);
        ushort4 u0  = *(const ushort4*)(hb + (size_t)q0.x * D);
        ushort4 u1  = *(const ushort4*)(hb + (size_t)q0.y * D);
        ushort4 u2  = *(const ushort4*)(hb + (size_t)q0.z * D);
        ushort4 u3  = *(const ushort4*)(hb + (size_t)q0.w * D);
        ushort4 u4  = *(const ushort4*)(hb + (size_t)q1.x * D);
        ushort4 u5  = *(const ushort4*)(hb + (size_t)q1.y * D);
        ushort4 u6  = *(const ushort4*)(hb + (size_t)q1.z * D);
        ushort4 u7  = *(const ushort4*)(hb + (size_t)q1.w * D);
        ushort4 u8  = *(const ushort4*)(hb + (size_t)q2.x * D);
        ushort4 u9  = *(const ushort4*)(hb + (size_t)q2.y * D);
        ushort4 u10 = *(const ushort4*)(hb + (size_t)q2.z * D);
        ushort4 u11 = *(const ushort4*)(hb + (size_t)q2.w * D);
        ushort4 u12 = *(const ushort4*)(hb + (size_t)q3.x * D);
        ushort4 u13 = *(const ushort4*)(hb + (size_t)q3.y * D);
        ushort4 u14 = *(const ushort4*)(hb + (size_t)q3.z * D);
        ushort4 u15 = *(const ushort4*)(hb + (size_t)q3.w * D);
        a0 += bf2f(u0.x);  a1 += bf2f(u0.y);  a2 += bf2f(u0.z);  a3 += bf2f(u0.w);
        a0 += bf2f(u1.x);  a1 += bf2f(u1.y);  a2 += bf2f(u1.z);  a3 += bf2f(u1.w);
        a0 += bf2f(u2.x);  a1 += bf2f(u2.y);  a2 += bf2f(u2.z);  a3 += bf2f(u2.w);
        a0 += bf2f(u3.x);  a1 += bf2f(u3.y);  a2 += bf2f(u3.z);  a3 += bf2f(u3.w);
        a0 += bf2f(u4.x);  a1 += bf2f(u4.y);  a2 += bf2f(u4.z);  a3 += bf2f(u4.w);
        a0 += bf2f(u5.x);  a1 += bf2f(u5.y);  a2 += bf2f(u5.z);  a3 += bf2f(u5.w);
        a0 += bf2f(u6.x);  a1 += bf2f(u6.y);  a2 += bf2f(u6.z);  a3 += bf2f(u6.w);
        a0 += bf2f(u7.x);  a1 += bf2f(u7.y);  a2 += bf2f(u7.z);  a3 += bf2f(u7.w);
        a0 += bf2f(u8.x);  a1 += bf2f(u8.y);  a2 += bf2f(u8.z);  a3 += bf2f(u8.w);
        a0 += bf2f(u9.x);  a1 += bf2f(u9.y);  a2 += bf2f(u9.z);  a3 += bf2f(u9.w);
        a0 += bf2f(u10.x); a1 += bf2f(u10.y); a2 += bf2f(u10.z); a3 += bf2f(u10.w);
        a0 += bf2f(u11.x); a1 += bf2f(u11.y); a2 += bf2f(u11.z); a3 += bf2f(u11.w);
        a0 += bf2f(u12.x); a1 += bf2f(u12.y); a2 += bf2f(u12.z); a3 += bf2f(u12.w);
        a0 += bf2f(u13.x); a1 += bf2f(u13.y); a2 += bf2f(u13.z); a3 += bf2f(u13.w);
        a0 += bf2f(u14.x); a1 += bf2f(u14.y); a2 += bf2f(u14.z); a3 += bf2f(u14.w);
        a0 += bf2f(u15.x); a1 += bf2f(u15.y); a2 += bf2f(u15.z); a3 += bf2f(u15.w);
    }
    for (; base + 8 <= dg; base += 8) {
        int4 q0 = *(const int4*)(idx + base);
        int4 q1 = *(const int4*)(idx + base + 4);
        ushort4 u0 = *(const ushort4*)(hb + (size_t)q0.x * D);
        ushort4 u1 = *(const ushort4*)(hb + (size_t)q0.y * D);
        ushort4 u2 = *(const ushort4*)(hb + (size_t)q0.z * D);
        ushort4 u3 = *(const ushort4*)(hb + (size_t)q0.w * D);
        ushort4 u4 = *(const ushort4*)(hb + (size_t)q1.x * D);
        ushort4 u5 = *(const ushort4*)(hb + (size_t)q1.y * D);
        ushort4 u6 = *(const ushort4*)(hb + (size_t)q1.z * D);
        ushort4 u7 = *(const ushort4*)(hb + (size_t)q1.w * D);
        a0 += bf2f(u0.x); a1 += bf2f(u0.y); a2 += bf2f(u0.z); a3 += bf2f(u0.w);
        a0 += bf2f(u1.x); a1 += bf2f(u1.y); a2 += bf2f(u1.z); a3 += bf2f(u1.w);
        a0 += bf2f(u2.x); a1 += bf2f(u2.y); a2 += bf2f(u2.z); a3 += bf2f(u2.w);
        a0 += bf2f(u3.x); a1 += bf2f(u3.y); a2 += bf2f(u3.z); a3 += bf2f(u3.w);
        a0 += bf2f(u4.x); a1 += bf2f(u4.y); a2 += bf2f(u4.z); a3 += bf2f(u4.w);
        a0 += bf2f(u5.x); a1 += bf2f(u5.y); a2 += bf2f(u5.z); a3 += bf2f(u5.w);
        a0 += bf2f(u6.x); a1 += bf2f(u6.y); a2 += bf2f(u6.z); a3 += bf2f(u6.w);
        a0 += bf2f(u7.x); a1 += bf2f(u7.y); a2 += bf2f(u7.z); a3 += bf2f(u7.w);
    }
    for (; base + 4 <= dg; base += 4) {
        int4 q0 = *(const int4*)(idx + base);
        ushort4 u0 = *(const ushort4*)(hb + (size_t)q0.x * D);
        ushort4 u1 = *(const ushort4*)(hb + (size_t)q0.y * D);
        ushort4 u2 = *(const ushort4*)(hb + (size_t)q0.z * D);
        ushort4 u3 = *(const ushort4*)(hb + (size_t)q0.w * D);
        a0 += bf2f(u0.x); a1 += bf2f(u0.y); a2 += bf2f(u0.z); a3 += bf2f(u0.w);
        a0 += bf2f(u1.x); a1 += bf2f(u1.y); a2 += bf2f(u1.z); a3 += bf2f(u1.w);
        a0 += bf2f(u2.x); a1 += bf2f(u2.y); a2 += bf2f(u2.z); a3 += bf2f(u2.w);
        a0 += bf2f(u3.x); a1 += bf2f(u3.y); a2 += bf2f(u3.z); a3 += bf2f(u3.w);
    }
    for (; base < dg; base++) {
        int c = idx[base];
        ushort4 u = *(const ushort4*)(hb + (size_t)c * D);
        a0 += bf2f(u.x); a1 += bf2f(u.y); a2 += bf2f(u.z); a3 += bf2f(u.w);
    }

    const float dr = rsqrtf((float)dgr);
    float4 o;
    o.x = a0 * dr; o.y = a1 * dr; o.z = a2 * dr; o.w = a3 * dr;
    *(float4*)(G + (size_t)r * D + ch) = o;

    // ---- block-level BN partial sums -> atomic fan-in to NPART rows ----
    __shared__ float ls[4][256], lss[4][256];
    ls[wave][ch] = o.x; ls[wave][ch + 1] = o.y; ls[wave][ch + 2] = o.z; ls[wave][ch + 3] = o.w;
    lss[wave][ch] = o.x * o.x; lss[wave][ch + 1] = o.y * o.y;
    lss[wave][ch + 2] = o.z * o.z; lss[wave][ch + 3] = o.w * o.w;
    __syncthreads();
    const int t = threadIdx.x;
    const int prow = (blockIdx.x & (NPART - 1)) * 256;
    atomicAdd(&psA[prow + t], ls[0][t] + ls[1][t] + ls[2][t] + ls[3][t]);
    atomicAdd(&psQ[prow + t], lss[0][t] + lss[1][t] + lss[2][t] + lss[3][t]);
}

// ------- final BN apply -> fp32 d_out (no relu); finalize folded into prologue -------
__global__ __launch_bounds__(256) void bn_apply_out(const float* __restrict__ G,
                                                    const float* __restrict__ psA,
                                                    const float* __restrict__ psQ,
                                                    const float* __restrict__ g,
                                                    const float* __restrict__ be,
                                                    float* __restrict__ Out) {
    __shared__ float ssc[256], ssh[256];
    const int tid = threadIdx.x;
    {
        float s = 0.f, q = 0.f;
        #pragma unroll
        for (int i = 0; i < NPART; i++) {
            s += psA[i * 256 + tid];
            q += psQ[i * 256 + tid];
        }
        float mu = s * (1.0f / N_NODES);
        float var = q * (1.0f / N_NODES) - mu * mu;
        float rstd = rsqrtf(var + 1e-5f);
        float sc = g[tid] * rstd;
        ssc[tid] = sc;
        ssh[tid] = be[tid] - mu * sc;
        __syncthreads();
    }
    const int rows_per_block = 32;
    const int r0 = blockIdx.x * rows_per_block;
    const int ch = (tid & 63) * 4;
    const int rsub = tid >> 6;
    float4 sc = *(const float4*)(ssc + ch);
    float4 sh = *(const float4*)(ssh + ch);
    for (int rr = rsub; rr < rows_per_block; rr += 4) {
        const size_t off = (size_t)(r0 + rr) * D + ch;
        float4 v = *(const float4*)(G + off);
        v.x = fmaf(v.x, sc.x, sh.x);
        v.y = fmaf(v.y, sc.y, sh.y);
        v.z = fmaf(v.z, sc.z, sh.z);
        v.w = fmaf(v.w, sc.w, sh.w);
        *(float4*)(Out + off) = v;
    }
}

extern "C" void kernel_launch(void* const* d_in, const int* in_sizes, int n_in,
                              void* d_out, int out_size, void* d_ws, size_t ws_size,
                              hipStream_t stream) {
    const float* x  = (const float*)d_in[0];
    const int*   ei = (const int*)d_in[1];
    const float* W1 = (const float*)d_in[2];
    const float* b1 = (const float*)d_in[3];
    const float* W2 = (const float*)d_in[4];
    const float* b2 = (const float*)d_in[5];
    const float* W3 = (const float*)d_in[6];
    const float* b3 = (const float*)d_in[7];
    const float* g1 = (const float*)d_in[8];
    const float* be1 = (const float*)d_in[9];
    const float* g2 = (const float*)d_in[10];
    const float* be2 = (const float*)d_in[11];
    const float* g3 = (const float*)d_in[12];
    const float* be3 = (const float*)d_in[13];

    char* ws = (char*)d_ws;
    // zeroed region: [0, 8MB + 128KB) = adj(8MB) + deg(32KB) + 6 psum arrays(96KB)
    unsigned*       adj  = (unsigned*)ws;                            // 8 MB (live through gemm1_and_nbrs)
    int*            deg  = (int*)(ws + (8 << 20));                   // 32 KB
    float*          psA0 = (float*)(ws + (8 << 20) + (32 << 10));    // 16 KB each
    float*          psQ0 = psA0 + NPART * 256;
    float*          psA1 = psQ0 + NPART * 256;
    float*          psQ1 = psA1 + NPART * 256;
    float*          psA2 = psQ1 + NPART * 256;
    float*          psQ2 = psA2 + NPART * 256;
    unsigned short* Wb1  = (unsigned short*)(ws + (8 << 20) + (128 << 10));  // 128 KB each
    unsigned short* Wb2  = (unsigned short*)(ws + (8 << 20) + (256 << 10));
    unsigned short* Wb3  = (unsigned short*)(ws + (8 << 20) + (384 << 10));
    int*            nbr_idx = (int*)  (ws + (9 << 20));              // 4 MB
    float*          G       = (float*)(ws + (13 << 20));             // 8 MB
    unsigned short* Hb      = (unsigned short*)(ws + (21 << 20));    // 4 MB

    hipMemsetAsync(ws, 0, (8 << 20) + (128 << 10), stream);

    // edges + self-loops + 3*64K weight conversions = 466944 threads = 1824 blocks exactly
    build_adj<<<1824, 256, 0, stream>>>(ei, adj, deg, W1, W2, W3, Wb1, Wb2, Wb3);

    // ---- Layer 1 gemm co-scheduled with neighbor-list build (independent work)
    gemm1_and_nbrs<<<256 + N_NODES / 4, 256, 0, stream>>>(x, Wb1, b1, deg, Hb, adj, nbr_idx);
    aggregate_bf16<<<AGG_BLOCKS, 256, 0, stream>>>(nbr_idx, deg, Hb, G, psA0, psQ0);

    dim3 ggrid(D / 128, N_NODES / 64);

    // ---- Layer 2 (BN1 finalize + apply + relu fused into gemm)
    gemm_mfma_bn<<<ggrid, 256, 0, stream>>>(G, psA0, psQ0, g1, be1, Wb2, b2, deg, Hb);
    aggregate_bf16<<<AGG_BLOCKS, 256, 0, stream>>>(nbr_idx, deg, Hb, G, psA1, psQ1);

    // ---- Layer 3 (BN2 finalize + apply + relu fused into gemm)
    gemm_mfma_bn<<<ggrid, 256, 0, stream>>>(G, psA1, psQ1, g2, be2, Wb3, b3, deg, Hb);
    aggregate_bf16<<<AGG_BLOCKS, 256, 0, stream>>>(nbr_idx, deg, Hb, G, psA2, psQ2);

    // ---- final BN3 finalize + apply -> d_out
    bn_apply_out<<<N_NODES / 32, 256, 0, stream>>>(G, psA2, psQ2, g3, be3, (float*)d_out);
}

// Round 7
// 213.679 us; speedup vs baseline: 1.0367x; 1.0367x over previous
//
#include <hip/hip_runtime.h>

#define N_NODES 8192
#define N_EDGES 262144
#define D 256
#define ADJ_WORDS 256     // 8192 bits per row / 32
#define MAX_DEG 128       // Poisson(33): P(deg>128) ~ 1e-40
#define AGG_BLOCKS 2048   // 4 waves/block, ONE row per wave -> 8192 waves
#define NPART 16          // BN partial-sum rows (atomicAdd fan-in: 2048/16 = 128 per addr)

typedef __attribute__((ext_vector_type(8))) short bf16x8;
typedef __attribute__((ext_vector_type(4))) float f32x4;

__device__ __forceinline__ short f2bf(float f) {
    unsigned u = __builtin_bit_cast(unsigned, f);
    u += 0x7fffu + ((u >> 16) & 1);   // round to nearest even
    return (short)(u >> 16);
}
__device__ __forceinline__ float bf2f(unsigned short u) {
    return __builtin_bit_cast(float, ((unsigned)u) << 16);
}

// ---- adjacency build (set-semantics bitmask + exact degree) + W->bf16 tail blocks ----
__global__ __launch_bounds__(256) void build_adj(const int* __restrict__ ei,
                                                 unsigned* __restrict__ adj,
                                                 int* __restrict__ deg,
                                                 const float* __restrict__ W1,
                                                 const float* __restrict__ W2,
                                                 const float* __restrict__ W3,
                                                 unsigned short* __restrict__ Wb1,
                                                 unsigned short* __restrict__ Wb2,
                                                 unsigned short* __restrict__ Wb3) {
    int i = blockIdx.x * 256 + threadIdx.x;
    if (i >= N_EDGES + N_NODES) {      // weight-conversion tail
        int j = i - (N_EDGES + N_NODES);          // 0 .. 196607
        int which = j >> 16, k = j & 65535;
        const float* src = which == 0 ? W1 : which == 1 ? W2 : W3;
        unsigned short* dst = which == 0 ? Wb1 : which == 1 ? Wb2 : Wb3;
        dst[k] = (unsigned short)f2bf(src[k]);
        return;
    }
    int r, c;
    if (i < N_EDGES) {
        r = ei[i];
        c = ei[N_EDGES + i];
    } else {
        r = i - N_EDGES;               // self loop
        c = r;
    }
    unsigned bit = 1u << (c & 31);
    unsigned old = atomicOr(&adj[r * ADJ_WORDS + (c >> 5)], bit);
    if (!(old & bit)) atomicAdd(&deg[r], 1);   // count only newly-set bits (set semantics)
}

// ----- bitmask -> neighbor index list, ONE WAVE per row (LDS-free, sync-free).
// Lane l owns words 4l..4l+3 (one uint4 = 16B load covers the whole 1KB row per wave).
// popc -> wave shuffle prefix scan -> per-lane bit extraction. -----
__device__ __forceinline__ void nbrs_row_wave(const unsigned* __restrict__ adj,
                                              int* __restrict__ nbr_idx, int r) {
    const int lane = threadIdx.x & 63;
    uint4 w = *(const uint4*)(adj + (size_t)r * ADJ_WORDS + lane * 4);
    int cnt = __popc(w.x) + __popc(w.y) + __popc(w.z) + __popc(w.w);
    int x = cnt;
    #pragma unroll
    for (int off = 1; off < 64; off <<= 1) {
        int v = __shfl_up(x, off, 64);
        if (lane >= off) x += v;
    }
    int base = x - cnt;                // exclusive prefix across the wave
    int* oi = nbr_idx + (size_t)r * MAX_DEG;
    unsigned ws[4] = {w.x, w.y, w.z, w.w};
    #pragma unroll
    for (int k = 0; k < 4; k++) {
        unsigned m = ws[k];
        const int cbase = (lane * 4 + k) * 32;
        while (m) {
            int b = __ffs(m) - 1;
            m &= m - 1;
            if (base < MAX_DEG) oi[base] = cbase + b;
            base++;
        }
    }
}

// -------- Hb(bf16) = dinv[m] * (bnapply(Xsrc fp32) @ W^T + b)  (MFMA 16x16x32 bf16) ----
// 64x64 output tile (2 blocks/CU so prologue/epilogue overlap across blocks).
// BN finalize folded in: APPLY blocks reduce NPART(16) atomic partial rows.
// dinv[m] = rsqrt(deg[m]) folded into the epilogue store (weight factoring).
template <bool APPLY, bool RELU>
__device__ __forceinline__ void gemm_body(const float* __restrict__ Xsrc,
                                          const float* __restrict__ psA,
                                          const float* __restrict__ psQ,
                                          const float* __restrict__ g,
                                          const float* __restrict__ be,
                                          const unsigned short* __restrict__ Wb,
                                          const float* __restrict__ bias,
                                          const int* __restrict__ deg,
                                          unsigned short* __restrict__ Hb,
                                          int bn, int bm) {
    __shared__ float ssc[256], ssh[256];
    const int tid = threadIdx.x;
    if (APPLY) {
        float s = 0.f, q = 0.f;
        #pragma unroll
        for (int i = 0; i < NPART; i++) {
            s += psA[i * 256 + tid];
            q += psQ[i * 256 + tid];
        }
        float mu = s * (1.0f / N_NODES);
        float var = q * (1.0f / N_NODES) - mu * mu;
        float rstd = rsqrtf(var + 1e-5f);
        float sc = g[tid] * rstd;
        ssc[tid] = sc;
        ssh[tid] = be[tid] - mu * sc;
        __syncthreads();
    }

    const int wave = tid >> 6, lane = tid & 63;
    const int l16 = lane & 15, q = lane >> 4;
    const int mrow = bm + wave * 16 + l16;      // each wave owns a 16-row m-frag

    f32x4 acc[4];
    #pragma unroll
    for (int j = 0; j < 4; j++) acc[j] = (f32x4){0.f, 0.f, 0.f, 0.f};

    for (int k0 = 0; k0 < D; k0 += 32) {
        const int kq = k0 + q * 8;
        bf16x8 xb;
        {
            const float* xr = Xsrc + (size_t)mrow * D + kq;
            float4 a = *(const float4*)xr;
            float4 b = *(const float4*)(xr + 4);
            float v[8] = {a.x, a.y, a.z, a.w, b.x, b.y, b.z, b.w};
            if (APPLY) {
                float4 sc0 = *(const float4*)(ssc + kq);
                float4 sc1 = *(const float4*)(ssc + kq + 4);
                float4 sh0 = *(const float4*)(ssh + kq);
                float4 sh1 = *(const float4*)(ssh + kq + 4);
                float sc[8] = {sc0.x, sc0.y, sc0.z, sc0.w, sc1.x, sc1.y, sc1.z, sc1.w};
                float sh[8] = {sh0.x, sh0.y, sh0.z, sh0.w, sh1.x, sh1.y, sh1.z, sh1.w};
                #pragma unroll
                for (int j = 0; j < 8; j++) {
                    v[j] = fmaf(v[j], sc[j], sh[j]);
                    if (RELU) v[j] = fmaxf(v[j], 0.0f);
                }
            }
            #pragma unroll
            for (int j = 0; j < 8; j++) xb[j] = f2bf(v[j]);
        }
        #pragma unroll
        for (int nf = 0; nf < 4; nf++) {
            bf16x8 wa = *(const bf16x8*)(Wb + (size_t)(bn + nf * 16 + l16) * D + kq);
            acc[nf] = __builtin_amdgcn_mfma_f32_16x16x32_bf16(wa, xb, acc[nf], 0, 0, 0);
        }
    }

    const float di = rsqrtf((float)deg[mrow]);  // fold dinv[m] into stored row
    #pragma unroll
    for (int nf = 0; nf < 4; nf++) {
        const int nb = bn + nf * 16 + q * 4;
        float4 b4 = *(const float4*)(bias + nb);
        short4 o;
        o.x = f2bf((acc[nf][0] + b4.x) * di);
        o.y = f2bf((acc[nf][1] + b4.y) * di);
        o.z = f2bf((acc[nf][2] + b4.z) * di);
        o.w = f2bf((acc[nf][3] + b4.w) * di);
        *(short4*)(Hb + (size_t)mrow * D + nb) = o;
    }
}

// ---- fused dispatch: layer-1 gemm (512 blocks, launched first) + build_nbrs
// (2048 blocks x 4 wave-rows, LDS/sync-free) — independent work co-scheduled ----
__global__ __launch_bounds__(256) void gemm1_and_nbrs(const float* __restrict__ x,
                                                      const unsigned short* __restrict__ Wb1,
                                                      const float* __restrict__ b1,
                                                      const int* __restrict__ deg,
                                                      unsigned short* __restrict__ Hb,
                                                      const unsigned* __restrict__ adj,
                                                      int* __restrict__ nbr_idx) {
    const int bg = blockIdx.x;
    if (bg < 512) {
        gemm_body<false, false>(x, nullptr, nullptr, nullptr, nullptr, Wb1, b1, deg, Hb,
                                (bg & 3) * 64, (bg >> 2) * 64);
    } else {
        const int r = (bg - 512) * 4 + (threadIdx.x >> 6);   // 4 rows per block, 1/wave
        nbrs_row_wave(adj, nbr_idx, r);
    }
}

__global__ __launch_bounds__(256) void gemm_mfma_bn(const float* __restrict__ Xsrc,
                                                    const float* __restrict__ psA,
                                                    const float* __restrict__ psQ,
                                                    const float* __restrict__ g,
                                                    const float* __restrict__ be,
                                                    const unsigned short* __restrict__ Wb,
                                                    const float* __restrict__ bias,
                                                    const int* __restrict__ deg,
                                                    unsigned short* __restrict__ Hb) {
    gemm_body<true, true>(Xsrc, psA, psQ, g, be, Wb, bias, deg, Hb,
                          blockIdx.x * 64, blockIdx.y * 64);
}

// ------- G[r,:] = dinv[r] * sum_j Hb[idx_j,:]  (Hb rows pre-scaled by dinv[c]).
// ONE row per wave, 64 lanes x ushort4 (8B) = one full row per load instruction.
// 16-deep main loop -> 16 independent gathers in flight per wave. idx loads int4.
// BN partials: LDS block-reduce then atomicAdd into NPART(16) partial rows. -------
__global__ __launch_bounds__(256) void aggregate_bf16(const int* __restrict__ nbr_idx,
                                                      const int* __restrict__ deg,
                                                      const unsigned short* __restrict__ Hb,
                                                      float* __restrict__ G,
                                                      float* __restrict__ psA,
                                                      float* __restrict__ psQ) {
    const int wave = threadIdx.x >> 6;
    const int lane = threadIdx.x & 63;
    const int ch = lane * 4;             // 4 channels per lane, 64 lanes = full row
    const int r = blockIdx.x * 4 + wave;

    const int dgr = deg[r];
    int dg = dgr; if (dg > MAX_DEG) dg = MAX_DEG;
    const int* idx = nbr_idx + (size_t)r * MAX_DEG;
    const unsigned short* hb = Hb + ch;

    float a0 = 0.f, a1 = 0.f, a2 = 0.f, a3 = 0.f;
    int base = 0;
    for (; base + 16 <= dg; base += 16) {         // 16 x 8B gathers in flight
        int4 q0 = *(const int4*)(idx + base);
        int4 q1 = *(const int4*)(idx + base + 4);
        int4 q2 = *(const int4*)(idx + base + 8);
        int4 q3 = *(const int4*)(idx + base + 12);
        ushort4 u0  = *(const ushort4*)(hb + (size_t)q0.x * D);
        ushort4 u1  = *(const ushort4*)(hb + (size_t)q0.y * D);
        ushort4 u2  = *(const ushort4*)(hb + (size_t)q0.z * D);
        ushort4 u3  = *(const ushort4*)(hb + (size_t)q0.w * D);
        ushort4 u4  = *(const ushort4*)(hb + (size_t)q1.x * D);
        ushort4 u5  = *(const ushort4*)(hb + (size_t)q1.y * D);
        ushort4 u6  = *(const ushort4*)(hb + (size_t)q1.z * D);
        ushort4 u7  = *(const ushort4*)(hb + (size_t)q1.w * D);
        ushort4 u8  = *(const ushort4*)(hb + (size_t)q2.x * D);
        ushort4 u9  = *(const ushort4*)(hb + (size_t)q2.y * D);
        ushort4 u10 = *(const ushort4*)(hb + (size_t)q2.z * D);
        ushort4 u11 = *(const ushort4*)(hb + (size_t)q2.w * D);
        ushort4 u12 = *(const ushort4*)(hb + (size_t)q3.x * D);
        ushort4 u13 = *(const ushort4*)(hb + (size_t)q3.y * D);
        ushort4 u14 = *(const ushort4*)(hb + (size_t)q3.z * D);
        ushort4 u15 = *(const ushort4*)(hb + (size_t)q3.w * D);
        a0 += bf2f(u0.x);  a1 += bf2f(u0.y);  a2 += bf2f(u0.z);  a3 += bf2f(u0.w);
        a0 += bf2f(u1.x);  a1 += bf2f(u1.y);  a2 += bf2f(u1.z);  a3 += bf2f(u1.w);
        a0 += bf2f(u2.x);  a1 += bf2f(u2.y);  a2 += bf2f(u2.z);  a3 += bf2f(u2.w);
        a0 += bf2f(u3.x);  a1 += bf2f(u3.y);  a2 += bf2f(u3.z);  a3 += bf2f(u3.w);
        a0 += bf2f(u4.x);  a1 += bf2f(u4.y);  a2 += bf2f(u4.z);  a3 += bf2f(u4.w);
        a0 += bf2f(u5.x);  a1 += bf2f(u5.y);  a2 += bf2f(u5.z);  a3 += bf2f(u5.w);
        a0 += bf2f(u6.x);  a1 += bf2f(u6.y);  a2 += bf2f(u6.z);  a3 += bf2f(u6.w);
        a0 += bf2f(u7.x);  a1 += bf2f(u7.y);  a2 += bf2f(u7.z);  a3 += bf2f(u7.w);
        a0 += bf2f(u8.x);  a1 += bf2f(u8.y);  a2 += bf2f(u8.z);  a3 += bf2f(u8.w);
        a0 += bf2f(u9.x);  a1 += bf2f(u9.y);  a2 += bf2f(u9.z);  a3 += bf2f(u9.w);
        a0 += bf2f(u10.x); a1 += bf2f(u10.y); a2 += bf2f(u10.z); a3 += bf2f(u10.w);
        a0 += bf2f(u11.x); a1 += bf2f(u11.y); a2 += bf2f(u11.z); a3 += bf2f(u11.w);
        a0 += bf2f(u12.x); a1 += bf2f(u12.y); a2 += bf2f(u12.z); a3 += bf2f(u12.w);
        a0 += bf2f(u13.x); a1 += bf2f(u13.y); a2 += bf2f(u13.z); a3 += bf2f(u13.w);
        a0 += bf2f(u14.x); a1 += bf2f(u14.y); a2 += bf2f(u14.z); a3 += bf2f(u14.w);
        a0 += bf2f(u15.x); a1 += bf2f(u15.y); a2 += bf2f(u15.z); a3 += bf2f(u15.w);
    }
    for (; base + 8 <= dg; base += 8) {
        int4 q0 = *(const int4*)(idx + base);
        int4 q1 = *(const int4*)(idx + base + 4);
        ushort4 u0 = *(const ushort4*)(hb + (size_t)q0.x * D);
        ushort4 u1 = *(const ushort4*)(hb + (size_t)q0.y * D);
        ushort4 u2 = *(const ushort4*)(hb + (size_t)q0.z * D);
        ushort4 u3 = *(const ushort4*)(hb + (size_t)q0.w * D);
        ushort4 u4 = *(const ushort4*)(hb + (size_t)q1.x * D);
        ushort4 u5 = *(const ushort4*)(hb + (size_t)q1.y * D);
        ushort4 u6 = *(const ushort4*)(hb + (size_t)q1.z * D);
        ushort4 u7 = *(const ushort4*)(hb + (size_t)q1.w * D);
        a0 += bf2f(u0.x); a1 += bf2f(u0.y); a2 += bf2f(u0.z); a3 += bf2f(u0.w);
        a0 += bf2f(u1.x); a1 += bf2f(u1.y); a2 += bf2f(u1.z); a3 += bf2f(u1.w);
        a0 += bf2f(u2.x); a1 += bf2f(u2.y); a2 += bf2f(u2.z); a3 += bf2f(u2.w);
        a0 += bf2f(u3.x); a1 += bf2f(u3.y); a2 += bf2f(u3.z); a3 += bf2f(u3.w);
        a0 += bf2f(u4.x); a1 += bf2f(u4.y); a2 += bf2f(u4.z); a3 += bf2f(u4.w);
        a0 += bf2f(u5.x); a1 += bf2f(u5.y); a2 += bf2f(u5.z); a3 += bf2f(u5.w);
        a0 += bf2f(u6.x); a1 += bf2f(u6.y); a2 += bf2f(u6.z); a3 += bf2f(u6.w);
        a0 += bf2f(u7.x); a1 += bf2f(u7.y); a2 += bf2f(u7.z); a3 += bf2f(u7.w);
    }
    for (; base + 4 <= dg; base += 4) {
        int4 q0 = *(const int4*)(idx + base);
        ushort4 u0 = *(const ushort4*)(hb + (size_t)q0.x * D);
        ushort4 u1 = *(const ushort4*)(hb + (size_t)q0.y * D);
        ushort4 u2 = *(const ushort4*)(hb + (size_t)q0.z * D);
        ushort4 u3 = *(const ushort4*)(hb + (size_t)q0.w * D);
        a0 += bf2f(u0.x); a1 += bf2f(u0.y); a2 += bf2f(u0.z); a3 += bf2f(u0.w);
        a0 += bf2f(u1.x); a1 += bf2f(u1.y); a2 += bf2f(u1.z); a3 += bf2f(u1.w);
        a0 += bf2f(u2.x); a1 += bf2f(u2.y); a2 += bf2f(u2.z); a3 += bf2f(u2.w);
        a0 += bf2f(u3.x); a1 += bf2f(u3.y); a2 += bf2f(u3.z); a3 += bf2f(u3.w);
    }
    for (; base < dg; base++) {
        int c = idx[base];
        ushort4 u = *(const ushort4*)(hb + (size_t)c * D);
        a0 += bf2f(u.x); a1 += bf2f(u.y); a2 += bf2f(u.z); a3 += bf2f(u.w);
    }

    const float dr = rsqrtf((float)dgr);
    float4 o;
    o.x = a0 * dr; o.y = a1 * dr; o.z = a2 * dr; o.w = a3 * dr;
    *(float4*)(G + (size_t)r * D + ch) = o;

    // ---- block-level BN partial sums -> atomic fan-in to NPART rows ----
    __shared__ float ls[4][256], lss[4][256];
    ls[wave][ch] = o.x; ls[wave][ch + 1] = o.y; ls[wave][ch + 2] = o.z; ls[wave][ch + 3] = o.w;
    lss[wave][ch] = o.x * o.x; lss[wave][ch + 1] = o.y * o.y;
    lss[wave][ch + 2] = o.z * o.z; lss[wave][ch + 3] = o.w * o.w;
    __syncthreads();
    const int t = threadIdx.x;
    const int prow = (blockIdx.x & (NPART - 1)) * 256;
    atomicAdd(&psA[prow + t], ls[0][t] + ls[1][t] + ls[2][t] + ls[3][t]);
    atomicAdd(&psQ[prow + t], lss[0][t] + lss[1][t] + lss[2][t] + lss[3][t]);
}

// ------- final BN apply -> fp32 d_out (no relu); finalize folded into prologue.
// 1024 blocks x 8 rows (4 blocks/CU) to shorten the tail of the last serial stage. -------
__global__ __launch_bounds__(256) void bn_apply_out(const float* __restrict__ G,
                                                    const float* __restrict__ psA,
                                                    const float* __restrict__ psQ,
                                                    const float* __restrict__ g,
                                                    const float* __restrict__ be,
                                                    float* __restrict__ Out) {
    __shared__ float ssc[256], ssh[256];
    const int tid = threadIdx.x;
    {
        float s = 0.f, q = 0.f;
        #pragma unroll
        for (int i = 0; i < NPART; i++) {
            s += psA[i * 256 + tid];
            q += psQ[i * 256 + tid];
        }
        float mu = s * (1.0f / N_NODES);
        float var = q * (1.0f / N_NODES) - mu * mu;
        float rstd = rsqrtf(var + 1e-5f);
        float sc = g[tid] * rstd;
        ssc[tid] = sc;
        ssh[tid] = be[tid] - mu * sc;
        __syncthreads();
    }
    const int rows_per_block = 8;
    const int r0 = blockIdx.x * rows_per_block;
    const int ch = (tid & 63) * 4;
    const int rsub = tid >> 6;
    float4 sc = *(const float4*)(ssc + ch);
    float4 sh = *(const float4*)(ssh + ch);
    for (int rr = rsub; rr < rows_per_block; rr += 4) {
        const size_t off = (size_t)(r0 + rr) * D + ch;
        float4 v = *(const float4*)(G + off);
        v.x = fmaf(v.x, sc.x, sh.x);
        v.y = fmaf(v.y, sc.y, sh.y);
        v.z = fmaf(v.z, sc.z, sh.z);
        v.w = fmaf(v.w, sc.w, sh.w);
        *(float4*)(Out + off) = v;
    }
}

extern "C" void kernel_launch(void* const* d_in, const int* in_sizes, int n_in,
                              void* d_out, int out_size, void* d_ws, size_t ws_size,
                              hipStream_t stream) {
    const float* x  = (const float*)d_in[0];
    const int*   ei = (const int*)d_in[1];
    const float* W1 = (const float*)d_in[2];
    const float* b1 = (const float*)d_in[3];
    const float* W2 = (const float*)d_in[4];
    const float* b2 = (const float*)d_in[5];
    const float* W3 = (const float*)d_in[6];
    const float* b3 = (const float*)d_in[7];
    const float* g1 = (const float*)d_in[8];
    const float* be1 = (const float*)d_in[9];
    const float* g2 = (const float*)d_in[10];
    const float* be2 = (const float*)d_in[11];
    const float* g3 = (const float*)d_in[12];
    const float* be3 = (const float*)d_in[13];

    char* ws = (char*)d_ws;
    // zeroed region: [0, 8MB + 128KB) = adj(8MB) + deg(32KB) + 6 psum arrays(96KB)
    unsigned*       adj  = (unsigned*)ws;                            // 8 MB (live through gemm1_and_nbrs)
    int*            deg  = (int*)(ws + (8 << 20));                   // 32 KB
    float*          psA0 = (float*)(ws + (8 << 20) + (32 << 10));    // 16 KB each
    float*          psQ0 = psA0 + NPART * 256;
    float*          psA1 = psQ0 + NPART * 256;
    float*          psQ1 = psA1 + NPART * 256;
    float*          psA2 = psQ1 + NPART * 256;
    float*          psQ2 = psA2 + NPART * 256;
    unsigned short* Wb1  = (unsigned short*)(ws + (8 << 20) + (128 << 10));  // 128 KB each
    unsigned short* Wb2  = (unsigned short*)(ws + (8 << 20) + (256 << 10));
    unsigned short* Wb3  = (unsigned short*)(ws + (8 << 20) + (384 << 10));
    int*            nbr_idx = (int*)  (ws + (9 << 20));              // 4 MB
    float*          G       = (float*)(ws + (13 << 20));             // 8 MB
    unsigned short* Hb      = (unsigned short*)(ws + (21 << 20));    // 4 MB

    hipMemsetAsync(ws, 0, (8 << 20) + (128 << 10), stream);

    // edges + self-loops + 3*64K weight conversions = 466944 threads = 1824 blocks exactly
    build_adj<<<1824, 256, 0, stream>>>(ei, adj, deg, W1, W2, W3, Wb1, Wb2, Wb3);

    // ---- Layer 1 gemm co-scheduled with neighbor-list build (independent work)
    gemm1_and_nbrs<<<512 + N_NODES / 4, 256, 0, stream>>>(x, Wb1, b1, deg, Hb, adj, nbr_idx);
    aggregate_bf16<<<AGG_BLOCKS, 256, 0, stream>>>(nbr_idx, deg, Hb, G, psA0, psQ0);

    dim3 ggrid(D / 64, N_NODES / 64);

    // ---- Layer 2 (BN1 finalize + apply + relu fused into gemm)
    gemm_mfma_bn<<<ggrid, 256, 0, stream>>>(G, psA0, psQ0, g1, be1, Wb2, b2, deg, Hb);
    aggregate_bf16<<<AGG_BLOCKS, 256, 0, stream>>>(nbr_idx, deg, Hb, G, psA1, psQ1);

    // ---- Layer 3 (BN2 finalize + apply + relu fused into gemm)
    gemm_mfma_bn<<<ggrid, 256, 0, stream>>>(G, psA1, psQ1, g2, be2, Wb3, b3, deg, Hb);
    aggregate_bf16<<<AGG_BLOCKS, 256, 0, stream>>>(nbr_idx, deg, Hb, G, psA2, psQ2);

    // ---- final BN3 finalize + apply -> d_out
    bn_apply_out<<<N_NODES / 8, 256, 0, stream>>>(G, psA2, psQ2, g3, be3, (float*)d_out);
}